// Round 4
// baseline (158.239 us; speedup 1.0000x reference)
//
#include <hip/hip_runtime.h>

#define NN 2048
#define CC 64
#define TT 64

// One wave = one row. Zero barriers, zero LDS allocations, no cross-wave traffic.
__global__ __launch_bounds__(256, 8) void cope_kernel(
    const float* __restrict__ q,
    const float* __restrict__ qk,
    const float* __restrict__ pos_emb,
    float* __restrict__ out)
{
    const int tid  = threadIdx.x;      // [0,256)
    const int lane = tid & 63;
    const int wv   = tid >> 6;         // wave id 0..3
    const int row  = (blockIdx.x << 2) | wv;
    const int urow = __builtin_amdgcn_readfirstlane(row);   // force SGPR for q addressing

    // ---- issue my 8 qk loads first (HBM latency ~900cy, hidden under E) ----
    // lane l owns row elements [32l, 32l+32): dense coverage across the 8 instrs
    const float4* qk4 = (const float4*)(qk + (size_t)row * NN);
    float4 v[8];
#pragma unroll
    for (int i = 0; i < 8; ++i) v[i] = qk4[lane * 8 + i];

    // ---- E[lane] = q[row,:] . pos_emb[:,lane]  (pos_emb is 16KB -> L1-hot) ----
    const float* qr = q + (size_t)urow * CC;   // uniform -> s_load
    float acc0 = 0.0f, acc1 = 0.0f;
#pragma unroll 4
    for (int c = 0; c < CC; c += 2) {
        acc0 = fmaf(qr[c],     pos_emb[c * TT + lane],       acc0);
        acc1 = fmaf(qr[c + 1], pos_emb[(c + 1) * TT + lane], acc1);
    }
    const float e_lo = acc0 + acc1;                       // lane t holds E[t]
    const float e_hi = __shfl(e_lo, min(lane + 1, 63), 64); // lane t holds E[min(t+1,63)]

    // ---- sigmoid of my 32 elements + lane sum ----
    float g[32];
#pragma unroll
    for (int i = 0; i < 8; ++i) {
        g[4 * i + 0] = v[i].x; g[4 * i + 1] = v[i].y;
        g[4 * i + 2] = v[i].z; g[4 * i + 3] = v[i].w;
    }
    float s = 0.0f;
#pragma unroll
    for (int k = 0; k < 32; ++k) {
        g[k] = __builtin_amdgcn_rcpf(1.0f + __expf(-g[k]));
        s += g[k];
    }

    // ---- wave-level inclusive suffix scan (64 lanes) -> exclusive suffix ----
    float inc = s;
#pragma unroll
    for (int o = 1; o < 64; o <<= 1) {
        float t = __shfl_down(inc, o, 64);
        if (lane + o < 64) inc += t;
    }
    const float X = inc - s;     // sum over lanes > mine

    // ---- per-element running suffix, clamp, register-gather interp, store ----
    float4* op = (float4*)(out + (size_t)row * NN);
    float run = 0.0f;
#pragma unroll
    for (int i = 7; i >= 0; --i) {
        float o4[4];
#pragma unroll
        for (int c = 3; c >= 0; --c) {
            run += g[4 * i + c];
            float P  = fminf(run + X, 63.0f);
            float fl = floorf(P);
            float w  = P - fl;
            int   i0 = (int)fl;
            float ef = __shfl(e_lo, i0, 64);   // E[i0]
            float ec = __shfl(e_hi, i0, 64);   // E[min(i0+1,63)]
            o4[c] = fmaf(w, ec - ef, ef);
        }
        op[lane * 8 + i] = make_float4(o4[0], o4[1], o4[2], o4[3]);
    }
}

extern "C" void kernel_launch(void* const* d_in, const int* in_sizes, int n_in,
                              void* d_out, int out_size, void* d_ws, size_t ws_size,
                              hipStream_t stream) {
    const float* q       = (const float*)d_in[0];
    const float* qk      = (const float*)d_in[1];
    const float* pos_emb = (const float*)d_in[2];
    float* out = (float*)d_out;

    dim3 grid((16 * 2048) / 4);   // one row per wave, 4 waves per block
    dim3 block(256);
    cope_kernel<<<grid, block, 0, stream>>>(q, qk, pos_emb, out);
}

// Round 5
// 144.448 us; speedup vs baseline: 1.0955x; 1.0955x over previous
//
#include <hip/hip_runtime.h>

#define NN 2048
#define CC 64
#define TT 64

__global__ __launch_bounds__(256, 8) void cope_kernel(
    const float* __restrict__ q,
    const float* __restrict__ qk,
    const float* __restrict__ pos_emb,
    float* __restrict__ out)
{
    const int tid  = threadIdx.x;      // [0,256)
    const int lane = tid & 63;
    const int wv   = tid >> 6;
    const int row  = blockIdx.x;       // one block per row

    __shared__ float e_lds[4][TT];     // per-wave private E copy
    __shared__ float wave_tot[4];

    // ---- qk row loads first (HBM ~900cy, hidden under E compute) ----
    const float4* qk4 = (const float4*)(qk + (size_t)row * NN);
    float4 a0 = qk4[2 * tid];
    float4 a1 = qk4[2 * tid + 1];

    // ---- per-wave E: lane (h=lane>>4, i=lane&15) accumulates E[4i..4i+4)
    //      over c ∈ {4j+h}; pos_emb read as coalesced float4 (L1-hot);
    //      q via wave-uniform scalar loads + cndmask select. ----
    {
        const int h = lane >> 4;
        const int i = lane & 15;
        const float* qr = q + (size_t)row * CC;        // uniform -> s_load
        const float4* pe4 = (const float4*)pos_emb;
        float4 acc = make_float4(0.f, 0.f, 0.f, 0.f);
#pragma unroll
        for (int j = 0; j < 16; ++j) {
            const float q0 = qr[4*j+0], q1 = qr[4*j+1];
            const float q2 = qr[4*j+2], q3 = qr[4*j+3];
            const float qa = (h & 1) ? q1 : q0;
            const float qb = (h & 1) ? q3 : q2;
            const float qc = (h & 2) ? qb : qa;        // = q[4j+h]
            const float4 p = pe4[(4*j + h) * (TT/4) + i];
            acc.x = fmaf(qc, p.x, acc.x);
            acc.y = fmaf(qc, p.y, acc.y);
            acc.z = fmaf(qc, p.z, acc.z);
            acc.w = fmaf(qc, p.w, acc.w);
        }
        // reduce the 4 h-group partials (lanes i, i+16, i+32, i+48)
        acc.x += __shfl_xor(acc.x, 16, 64);
        acc.y += __shfl_xor(acc.y, 16, 64);
        acc.z += __shfl_xor(acc.z, 16, 64);
        acc.w += __shfl_xor(acc.w, 16, 64);
        acc.x += __shfl_xor(acc.x, 32, 64);
        acc.y += __shfl_xor(acc.y, 32, 64);
        acc.z += __shfl_xor(acc.z, 32, 64);
        acc.w += __shfl_xor(acc.w, 32, 64);
        if (lane < 16)
            *(float4*)&e_lds[wv][4 * i] = acc;         // ds_write_b128
    }

    // ---- sigmoid of my 8 elements + thread sum ----
    float g[8];
    g[0] = a0.x; g[1] = a0.y; g[2] = a0.z; g[3] = a0.w;
    g[4] = a1.x; g[5] = a1.y; g[6] = a1.z; g[7] = a1.w;
    float s = 0.f;
#pragma unroll
    for (int k = 0; k < 8; ++k) {
        g[k] = __builtin_amdgcn_rcpf(1.0f + __expf(-g[k]));
        s += g[k];
    }

    // ---- wave-level inclusive suffix scan ----
    float inc = s;
#pragma unroll
    for (int o = 1; o < 64; o <<= 1) {
        float t = __shfl_down(inc, o, 64);
        if (lane + o < 64) inc += t;
    }
    const float X = inc - s;            // exclusive suffix within wave
    if (lane == 0) wave_tot[wv] = inc;
    __syncthreads();                    // the ONLY barrier (loads already consumed)

    float W = 0.f;
#pragma unroll
    for (int w2 = 0; w2 < 4; ++w2)
        if (w2 > wv) W += wave_tot[w2];
    const float base = X + W;           // exclusive suffix across the row

    // ---- gather-interp; fast path when all 8 outputs clamp to E[63] ----
    float4 o0, o1;
    if (base >= 63.0f) {
        const float e63 = e_lds[wv][63];   // broadcast read
        o0 = make_float4(e63, e63, e63, e63);
        o1 = o0;
    } else {
        float o8[8];
        float run = 0.f;
#pragma unroll
        for (int k = 7; k >= 0; --k) {
            run += g[k];
            float P  = fminf(run + base, 63.0f);
            float fl = floorf(P);
            float w  = P - fl;
            int   i0 = (int)fl;
            int   i1 = min(i0 + 1, 63);
            float ef = e_lds[wv][i0];
            float ec = e_lds[wv][i1];
            o8[k] = fmaf(w, ec - ef, ef);
        }
        o0 = make_float4(o8[0], o8[1], o8[2], o8[3]);
        o1 = make_float4(o8[4], o8[5], o8[6], o8[7]);
    }

    float4* op = (float4*)(out + (size_t)row * NN);
    op[2 * tid]     = o0;
    op[2 * tid + 1] = o1;
}

extern "C" void kernel_launch(void* const* d_in, const int* in_sizes, int n_in,
                              void* d_out, int out_size, void* d_ws, size_t ws_size,
                              hipStream_t stream) {
    const float* q       = (const float*)d_in[0];
    const float* qk      = (const float*)d_in[1];
    const float* pos_emb = (const float*)d_in[2];
    float* out = (float*)d_out;

    dim3 grid(16 * 2048);   // one block per row
    dim3 block(256);
    cope_kernel<<<grid, block, 0, stream>>>(q, qk, pos_emb, out);
}

// Round 6
// 139.481 us; speedup vs baseline: 1.1345x; 1.0356x over previous
//
#include <hip/hip_runtime.h>

#define NN 2048
#define CC 64
#define TT 64

__global__ __launch_bounds__(256, 8) void cope_kernel(
    const float* __restrict__ q,
    const float* __restrict__ qk,
    const float* __restrict__ pos_emb,
    float* __restrict__ out)
{
    const int tid  = threadIdx.x;      // [0,256)
    const int lane = tid & 63;
    const int wv   = tid >> 6;
    const int row  = blockIdx.x;       // one block per row

    __shared__ float e_lds[TT];        // one shared E row (written disjointly)
    __shared__ float wave_tot[4];

    // ---- qk row loads first (latency hidden under E compute) ----
    const float4* qk4 = (const float4*)(qk + (size_t)row * NN);
    float4 a0 = qk4[2 * tid];
    float4 a1 = qk4[2 * tid + 1];

    // ---- non-redundant E: wave wv owns E[16wv .. 16wv+16).
    //      lane (h=lane>>4, i=lane&15) accumulates over c in [16h,16h+16).
    //      16 FMA/thread, 2 shfl_xor to reduce h-groups, no barrier. ----
    {
        const int h = lane >> 4;
        const int i = lane & 15;
        const int t = 16 * wv + i;
        const float4* q4 = (const float4*)(q + (size_t)row * CC + 16 * h);
        float qv[16];
        *(float4*)&qv[0]  = q4[0];     // 4 broadcast 16B loads (64B/wave each)
        *(float4*)&qv[4]  = q4[1];
        *(float4*)&qv[8]  = q4[2];
        *(float4*)&qv[12] = q4[3];
        const float* pe = pos_emb + (size_t)(16 * h) * TT + t;
        float acc = 0.f;
#pragma unroll
        for (int cc = 0; cc < 16; ++cc)
            acc = fmaf(qv[cc], pe[cc * TT], acc);
        acc += __shfl_xor(acc, 16, 64);    // fold h=1/3 into h=0/2
        acc += __shfl_xor(acc, 32, 64);    // fold h=2 into h=0
        if (lane < 16)
            e_lds[16 * wv + lane] = acc;   // disjoint 16-float chunk per wave
    }

    // ---- sigmoid of my 8 elements + thread sum ----
    float g[8];
    g[0] = a0.x; g[1] = a0.y; g[2] = a0.z; g[3] = a0.w;
    g[4] = a1.x; g[5] = a1.y; g[6] = a1.z; g[7] = a1.w;
    float s = 0.f;
#pragma unroll
    for (int k = 0; k < 8; ++k) {
        g[k] = __builtin_amdgcn_rcpf(1.0f + __expf(-g[k]));
        s += g[k];
    }

    // ---- wave-level inclusive suffix scan ----
    float inc = s;
#pragma unroll
    for (int o = 1; o < 64; o <<= 1) {
        float t = __shfl_down(inc, o, 64);
        if (lane + o < 64) inc += t;
    }
    const float X = inc - s;            // exclusive suffix within wave
    if (lane == 0) wave_tot[wv] = inc;

    __syncthreads();                    // the ONLY barrier: publishes e_lds + wave_tot

    float W = 0.f;
#pragma unroll
    for (int w2 = 0; w2 < 4; ++w2)
        if (w2 > wv) W += wave_tot[w2];
    const float base = X + W;           // exclusive suffix across the row

    // ---- gather-interp; fast path when all 8 outputs clamp to E[63] ----
    float4 o0, o1;
    if (base >= 63.0f) {
        const float e63 = e_lds[63];    // broadcast read
        o0 = make_float4(e63, e63, e63, e63);
        o1 = o0;
    } else {
        float o8[8];
        float run = 0.f;
#pragma unroll
        for (int k = 7; k >= 0; --k) {
            run += g[k];
            float P  = fminf(run + base, 63.0f);
            float fl = floorf(P);
            float w  = P - fl;
            int   i0 = (int)fl;
            int   i1 = min(i0 + 1, 63);
            float ef = e_lds[i0];
            float ec = e_lds[i1];
            o8[k] = fmaf(w, ec - ef, ef);
        }
        o0 = make_float4(o8[0], o8[1], o8[2], o8[3]);
        o1 = make_float4(o8[4], o8[5], o8[6], o8[7]);
    }

    float4* op = (float4*)(out + (size_t)row * NN);
    op[2 * tid]     = o0;
    op[2 * tid + 1] = o1;
}

extern "C" void kernel_launch(void* const* d_in, const int* in_sizes, int n_in,
                              void* d_out, int out_size, void* d_ws, size_t ws_size,
                              hipStream_t stream) {
    const float* q       = (const float*)d_in[0];
    const float* qk      = (const float*)d_in[1];
    const float* pos_emb = (const float*)d_in[2];
    float* out = (float*)d_out;

    dim3 grid(16 * 2048);   // one block per row
    dim3 block(256);
    cope_kernel<<<grid, block, 0, stream>>>(q, qk, pos_emb, out);
}

// Round 7
// 120.086 us; speedup vs baseline: 1.3177x; 1.1615x over previous
//
#include <hip/hip_runtime.h>

#define NN 2048
#define CC 64
#define TT 64
#define NROWS (16 * 2048)

// ---------- Kernel A: E[row][t] = q[row,:] . pos_emb[:,t]  (8 MB out) ----------
__global__ __launch_bounds__(256, 4) void e_kernel(
    const float* __restrict__ q,
    const float* __restrict__ pos_emb,
    float* __restrict__ E)
{
    const int lane = threadIdx.x & 63;
    const int wv   = threadIdx.x >> 6;
    const int row  = blockIdx.x * 4 + wv;
    const int urow = __builtin_amdgcn_readfirstlane(row);   // wave-uniform -> s_load
    const float* qr = q + (size_t)urow * CC;
    const float* pe = pos_emb + lane;
    float acc0 = 0.f, acc1 = 0.f, acc2 = 0.f, acc3 = 0.f;
#pragma unroll
    for (int c = 0; c < CC; c += 4) {
        acc0 = fmaf(qr[c + 0], pe[(c + 0) * TT], acc0);
        acc1 = fmaf(qr[c + 1], pe[(c + 1) * TT], acc1);
        acc2 = fmaf(qr[c + 2], pe[(c + 2) * TT], acc2);
        acc3 = fmaf(qr[c + 3], pe[(c + 3) * TT], acc3);
    }
    E[(size_t)urow * TT + lane] = (acc0 + acc1) + (acc2 + acc3);
}

// ---------- Kernel B: the streaming pass (no E compute, tiny reg state) ----------
__global__ __launch_bounds__(256, 8) void cope_kernel(
    const float* __restrict__ qk,
    const float* __restrict__ E,
    float* __restrict__ out)
{
    const int tid  = threadIdx.x;      // [0,256)
    const int lane = tid & 63;
    const int wv   = tid >> 6;
    const int row  = blockIdx.x;       // one block per row

    __shared__ float e_lds[TT];
    __shared__ float wave_tot[4];

    // qk row: 8 contiguous elems/thread, coalesced
    const float4* qk4 = (const float4*)(qk + (size_t)row * NN);
    float4 a0 = qk4[2 * tid];
    float4 a1 = qk4[2 * tid + 1];

    // stage this row's E (256 B) into LDS
    if (tid < 16)
        ((float4*)e_lds)[tid] = ((const float4*)(E + (size_t)row * TT))[tid];

    // sigmoid + thread sum
    float g[8];
    g[0] = a0.x; g[1] = a0.y; g[2] = a0.z; g[3] = a0.w;
    g[4] = a1.x; g[5] = a1.y; g[6] = a1.z; g[7] = a1.w;
    float s = 0.f;
#pragma unroll
    for (int k = 0; k < 8; ++k) {
        g[k] = __builtin_amdgcn_rcpf(1.0f + __expf(-g[k]));
        s += g[k];
    }

    // wave-level inclusive suffix scan
    float inc = s;
#pragma unroll
    for (int o = 1; o < 64; o <<= 1) {
        float t = __shfl_down(inc, o, 64);
        if (lane + o < 64) inc += t;
    }
    const float X = inc - s;            // exclusive suffix within wave
    if (lane == 0) wave_tot[wv] = inc;

    __syncthreads();                    // ONLY barrier: publishes e_lds + wave_tot

    float W = 0.f;
#pragma unroll
    for (int w2 = 0; w2 < 4; ++w2)
        if (w2 > wv) W += wave_tot[w2];
    const float base = X + W;

    float4 o0, o1;
    if (base >= 63.0f) {                // all 8 outputs clamp to E[63]
        const float e63 = e_lds[63];
        o0 = make_float4(e63, e63, e63, e63);
        o1 = o0;
    } else {
        float o8[8];
        float run = 0.f;
#pragma unroll
        for (int k = 7; k >= 0; --k) {
            run += g[k];
            float P  = fminf(run + base, 63.0f);
            float fl = floorf(P);
            float w  = P - fl;
            int   i0 = (int)fl;
            int   i1 = min(i0 + 1, 63);
            float ef = e_lds[i0];
            float ec = e_lds[i1];
            o8[k] = fmaf(w, ec - ef, ef);
        }
        o0 = make_float4(o8[0], o8[1], o8[2], o8[3]);
        o1 = make_float4(o8[4], o8[5], o8[6], o8[7]);
    }

    float4* op = (float4*)(out + (size_t)row * NN);
    op[2 * tid]     = o0;
    op[2 * tid + 1] = o1;
}

// ---------- Fallback (ws too small): round-1 fused kernel, known-good 105 us ----------
__global__ __launch_bounds__(256, 4) void cope_fused(
    const float* __restrict__ q,
    const float* __restrict__ qk,
    const float* __restrict__ pos_emb,
    float* __restrict__ out)
{
    const int tid  = threadIdx.x;
    const int lane = tid & 63;
    const int wv   = tid >> 6;
    const int row  = blockIdx.x;

    __shared__ float q_lds[CC];
    __shared__ float e_part[4][TT];
    __shared__ float e_row[TT];
    __shared__ float wave_tot[4];

    const size_t rowN = (size_t)row * NN;
    const float4* qk4 = (const float4*)(qk + rowN);
    float4 v0 = qk4[tid * 2];
    float4 v1 = qk4[tid * 2 + 1];

    if (tid < CC) q_lds[tid] = q[(size_t)row * CC + tid];
    __syncthreads();
    {
        const int t  = tid & 63;
        const int c0 = (tid >> 6) * 16;
        float acc = 0.0f;
#pragma unroll
        for (int cc = 0; cc < 16; ++cc)
            acc = fmaf(q_lds[c0 + cc], pos_emb[(c0 + cc) * TT + t], acc);
        e_part[tid >> 6][t] = acc;
    }
    __syncthreads();
    if (tid < TT)
        e_row[tid] = e_part[0][tid] + e_part[1][tid] + e_part[2][tid] + e_part[3][tid];

    float g[8];
    g[0] = v0.x; g[1] = v0.y; g[2] = v0.z; g[3] = v0.w;
    g[4] = v1.x; g[5] = v1.y; g[6] = v1.z; g[7] = v1.w;
#pragma unroll
    for (int k = 0; k < 8; ++k)
        g[k] = 1.0f / (1.0f + __expf(-g[k]));

    float s = 0.0f;
#pragma unroll
    for (int k = 0; k < 8; ++k) s += g[k];

    float inc = s;
#pragma unroll
    for (int o = 1; o < 64; o <<= 1) {
        float tmp = __shfl_down(inc, o, 64);
        if (lane + o < 64) inc += tmp;
    }
    const float X = inc - s;
    if (lane == 0) wave_tot[wv] = inc;
    __syncthreads();

    float W = 0.0f;
#pragma unroll
    for (int w2 = 0; w2 < 4; ++w2)
        if (w2 > wv) W += wave_tot[w2];
    const float base = X + W;

    float o8[8];
    float run = 0.0f;
#pragma unroll
    for (int k = 7; k >= 0; --k) {
        run += g[k];
        float P  = fminf(run + base, 63.0f);
        float fl = floorf(P);
        float w_ = P - fl;
        int   i0 = (int)fl;
        int   i1 = (int)ceilf(P);
        float ef = e_row[i0];
        float ec = e_row[i1];
        o8[k] = fmaf(w_, ec - ef, ef);
    }

    float4* out4 = (float4*)(out + rowN);
    out4[tid * 2]     = make_float4(o8[0], o8[1], o8[2], o8[3]);
    out4[tid * 2 + 1] = make_float4(o8[4], o8[5], o8[6], o8[7]);
}

extern "C" void kernel_launch(void* const* d_in, const int* in_sizes, int n_in,
                              void* d_out, int out_size, void* d_ws, size_t ws_size,
                              hipStream_t stream) {
    const float* q       = (const float*)d_in[0];
    const float* qk      = (const float*)d_in[1];
    const float* pos_emb = (const float*)d_in[2];
    float* out = (float*)d_out;

    const size_t e_bytes = (size_t)NROWS * TT * sizeof(float);
    if (ws_size >= e_bytes) {
        float* E = (float*)d_ws;
        e_kernel<<<dim3(NROWS / 4), dim3(256), 0, stream>>>(q, pos_emb, E);
        cope_kernel<<<dim3(NROWS), dim3(256), 0, stream>>>(qk, E, out);
    } else {
        cope_fused<<<dim3(NROWS), dim3(256), 0, stream>>>(q, qk, pos_emb, out);
    }
}